// Round 13
// baseline (434.469 us; speedup 1.0000x reference)
//
#include <hip/hip_runtime.h>

#define N_NODES 40000
#define N_EDGES 640000
#define EMB 128
#define NF ((size_t)N_NODES * EMB)
#define RCP_N (1.0f / (float)N_NODES)
#define BN_EPS 1e-5f
#define CAP 64          // fixed bucket capacity (avg deg 16; P(>64) ~ 1e-18)
#define NSLICE 16       // stats accumulator slices (atomic contention fix)
#define STB (NSLICE * 256)   // floats per sliced stat block
#define GB 625          // GEMM grid: 64-row tiles, 256 threads

typedef _Float16 f16x8v __attribute__((ext_vector_type(8)));
typedef float f32x4v __attribute__((ext_vector_type(4)));
typedef unsigned short ushort8v __attribute__((ext_vector_type(8)));

__device__ __forceinline__ unsigned short f2h(float v) {
    return __builtin_bit_cast(unsigned short, (_Float16)v);
}
__device__ __forceinline__ float h2f(unsigned short u) {
    return (float)__builtin_bit_cast(_Float16, u);
}

// Sum NSLICE slices of a stat block -> bn scale/shift (threads t<128)
__device__ __forceinline__ void bn_prep(
    const float* __restrict__ stat, const float* __restrict__ g,
    const float* __restrict__ bt, float* C, float* D, int t)
{
    if (t < 128) {
        float sm = 0.f, sq = 0.f;
        #pragma unroll
        for (int s = 0; s < NSLICE; ++s) {
            sm += stat[s * 256 + t];
            sq += stat[s * 256 + 128 + t];
        }
        float m = sm * RCP_N;
        float v = sq * RCP_N - m * m;
        float a = g[t] * rsqrtf(v + BN_EPS);
        C[t] = a; D[t] = bt[t] - m * a;
    }
}

// ---------------------------------------------------------------------------
// Merged edge pass + initial node MLP (tiny LDS so edge occupancy unhurt):
//   blocks [0,625): P(f16) = node_attr @ W0 + b0, sliced col stats
//   blocks [625,3125): per-edge atomics (1 edge/thread = max outstanding)
// ---------------------------------------------------------------------------
__global__ __launch_bounds__(256) void edge_init_kernel(
    const float* __restrict__ na, const float* __restrict__ W0,
    const float* __restrict__ b0, unsigned short* __restrict__ Z,
    float* __restrict__ st,
    const int* __restrict__ ei, const float* __restrict__ ea,
    unsigned long long* __restrict__ scP, unsigned* __restrict__ cursor,
    int* __restrict__ slot)
{
    __shared__ float red[256];
    const int blk = blockIdx.x;
    const int t = threadIdx.x;
    if (blk < 625) {
        int col = t & 127, rh = t >> 7;
        float w0 = W0[col], w1 = W0[128 + col], bb = b0[col];
        int rbase = blk * 64;
        float sm = 0.f, sq = 0.f;
        #pragma unroll 4
        for (int i = 0; i < 32; ++i) {
            int r = rbase + rh + i * 2;
            float2 nv = *(const float2*)&na[r * 2];
            float v = fmaf(nv.x, w0, fmaf(nv.y, w1, bb));
            Z[(size_t)r * 128 + col] = f2h(v);
            sm += v; sq += v * v;
        }
        float* stS = st + (blk & (NSLICE - 1)) * 256;
        red[t] = sm; __syncthreads();
        if (t < 128) atomicAdd(&stS[t], red[t] + red[t + 128]);
        __syncthreads();
        red[t] = sq; __syncthreads();
        if (t < 128) atomicAdd(&stS[128 + t], red[t] + red[t + 128]);
    } else {
        int e = (blk - 625) * 256 + t;     // 2500*256 == N_EDGES
        int r = ei[e];
        int d = ei[N_EDGES + e];
        int fx = (int)rintf(ea[e] * 65536.0f);
        unsigned long long add =
            (((unsigned long long)(unsigned)(fx + 0x40000000)) << 20) | 1ULL;
        atomicAdd(&scP[r], add);
        unsigned pos = atomicAdd(&cursor[d], 1u);
        slot[(size_t)d * CAP + (pos < CAP ? pos : CAP - 1)] = r;
    }
}

// Decode scP -> sN, cN + scalar moments; cursor -> f32 deg.  grid 157
__global__ __launch_bounds__(256) void decode_kernel(
    const unsigned long long* __restrict__ scP, const unsigned* __restrict__ cursor,
    float* __restrict__ sN, float* __restrict__ cN, float* __restrict__ dgf,
    float* __restrict__ mom)
{
    int t = threadIdx.x;
    int i = blockIdx.x * 256 + t;
    float a0 = 0.f, a1 = 0.f, a2 = 0.f, a3 = 0.f, a4 = 0.f;
    if (i < N_NODES) {
        unsigned long long v = scP[i];
        unsigned cnt = (unsigned)(v & 0xFFFFFULL);
        long long sp = (long long)(v >> 20) - ((long long)cnt << 30);
        float s = (float)sp * (1.0f / 65536.0f);
        float c = (float)cnt;
        sN[i] = s; cN[i] = c;
        dgf[i] = (float)cursor[i];
        a0 = s; a1 = s * s; a2 = c; a3 = c * c; a4 = s * c;
    }
    #pragma unroll
    for (int off = 32; off > 0; off >>= 1) {
        a0 += __shfl_down(a0, off);
        a1 += __shfl_down(a1, off);
        a2 += __shfl_down(a2, off);
        a3 += __shfl_down(a3, off);
        a4 += __shfl_down(a4, off);
    }
    if ((t & 63) == 0) {
        atomicAdd(&mom[0], a0);
        atomicAdd(&mom[1], a1);
        atomicAdd(&mom[2], a2);
        atomicAdd(&mom[3], a3);
        atomicAdd(&mom[4], a4);
    }
}

// ---------------------------------------------------------------------------
// Weight prep: Wt[mat][n][k] = f16(W[mat][k][n]), 12 matrices of 128x128.
// ---------------------------------------------------------------------------
__global__ __launch_bounds__(256) void wprep_kernel(
    const float* __restrict__ Wnode, const float* __restrict__ Wnb,
    const float* __restrict__ Wm1, const float* __restrict__ Wm2,
    unsigned short* __restrict__ Wt)
{
    __shared__ float tile[32][129];
    int b = blockIdx.x;
    int mat = b >> 2, kc = (b & 3) * 32;
    int grp = mat / 3, lay = mat % 3;
    const float* src = (grp == 0) ? Wnode : (grp == 1) ? Wnb : (grp == 2) ? Wm1 : Wm2;
    src += (size_t)lay * 16384;
    int t = threadIdx.x;
    #pragma unroll
    for (int i = 0; i < 16; ++i) {
        int idx = t + i * 256;
        int r = idx >> 7, n = idx & 127;
        tile[r][n] = src[(size_t)(kc + r) * 128 + n];
    }
    __syncthreads();
    int n = t >> 1, h = (t & 1) * 16;
    ushort8v o0, o1;
    #pragma unroll
    for (int j = 0; j < 8; ++j) o0[j] = f2h(tile[h + j][n]);
    #pragma unroll
    for (int j = 0; j < 8; ++j) o1[j] = f2h(tile[h + 8 + j][n]);
    unsigned short* dst = &Wt[(size_t)mat * 16384 + n * 128 + kc + h];
    *(ushort8v*)dst = o0;
    *(ushort8v*)(dst + 8) = o1;
}

// ---------------------------------------------------------------------------
// GEMM core: MFMA from afrag (regs) + swizzled LDS B, epilogue with bias,
// f16 write, sliced stats.  wave = 16 rows x 128 cols, 4 waves = 64 rows.
// ---------------------------------------------------------------------------
template<bool RSC>
__device__ __forceinline__ void gemm_core(
    int row0, int t, int slice, f16x8v afrag[4],
    const float* __restrict__ bias, const float* __restrict__ rowscale,
    unsigned short* __restrict__ Out, float* __restrict__ stats_out,
    const unsigned short* Bs, float (*redS)[128], float (*redQ)[128])
{
    const int w = t >> 6, lane = t & 63;
    const int la = lane & 15, lb = lane >> 4;
    const int kb = lb * 8;

    f32x4v acc[8];
    #pragma unroll
    for (int c = 0; c < 8; ++c) acc[c] = (f32x4v){0.f, 0.f, 0.f, 0.f};

    #pragma unroll
    for (int c = 0; c < 8; ++c) {
        int bn_ = (c << 4) + la;
        int bbase = bn_ * 128;
        int bswz = (bn_ & 7) << 3;
        #pragma unroll
        for (int s = 0; s < 4; ++s) {
            f16x8v bf = *(const f16x8v*)&Bs[(bbase + s * 32 + kb) ^ bswz];
            acc[c] = __builtin_amdgcn_mfma_f32_16x16x32_f16(
                afrag[s], bf, acc[c], 0, 0, 0);
        }
    }

    const int orow0 = row0 + (w << 4) + lb * 4;
    float rsj[4];
    if (RSC) {
        #pragma unroll
        for (int j = 0; j < 4; ++j) rsj[j] = rowscale[orow0 + j];
    }
    float csum[8], csq[8];
    #pragma unroll
    for (int c = 0; c < 8; ++c) {
        int col = (c << 4) + la;
        float bc = bias[col];
        float s0 = 0.f, s1 = 0.f;
        #pragma unroll
        for (int j = 0; j < 4; ++j) {
            float v = acc[c][j] + (RSC ? rsj[j] * bc : bc);
            Out[(size_t)(orow0 + j) * 128 + col] = f2h(v);
            s0 += v; s1 += v * v;
        }
        csum[c] = s0; csq[c] = s1;
    }
    #pragma unroll
    for (int c = 0; c < 8; ++c) {
        csum[c] += __shfl_xor(csum[c], 16);
        csum[c] += __shfl_xor(csum[c], 32);
        csq[c]  += __shfl_xor(csq[c], 16);
        csq[c]  += __shfl_xor(csq[c], 32);
    }
    if (lane < 16) {
        #pragma unroll
        for (int c = 0; c < 8; ++c) {
            redS[w][(c << 4) + lane] = csum[c];
            redQ[w][(c << 4) + lane] = csq[c];
        }
    }
    __syncthreads();
    float* stS = stats_out + slice * 256;
    if (t < 128) {
        atomicAdd(&stS[t], redS[0][t] + redS[1][t] + redS[2][t] + redS[3][t]);
        atomicAdd(&stS[128 + t], redQ[0][t] + redQ[1][t] + redQ[2][t] + redQ[3][t]);
    }
}

// Stage B (128x128 f16) into LDS with XOR swizzle (R5-proven pattern)
__device__ __forceinline__ void stage_B(
    const unsigned short* __restrict__ Wt, unsigned short* Bs, int t)
{
    #pragma unroll
    for (int i = 0; i < 8; ++i) {
        int cch = t + i * 256;
        int n = cch >> 4, off = (cch & 15) << 3;
        ushort8v w = *(const ushort8v*)&Wt[n * 128 + off];
        *(ushort8v*)&Bs[(n * 128 + off) ^ ((n & 7) << 3)] = w;
    }
}

// Load afrag from global A with optional transforms (AMODE 0/1/2)
template<int AMODE>
__device__ __forceinline__ void load_afrag_global(
    int row0, int t, f16x8v afrag[4],
    const unsigned short* __restrict__ A, const unsigned short* __restrict__ A2,
    const float* C1, const float* D1, const float* C2, const float* D2,
    const float* AE, const float* BE, const float* CE,
    const float* __restrict__ sN, const float* __restrict__ cN)
{
    const int w = t >> 6, lane = t & 63;
    const int la = lane & 15, lb = lane >> 4;
    const int ar = row0 + (w << 4) + la;
    const int kb = lb * 8;
    #pragma unroll
    for (int s = 0; s < 4; ++s) {
        ushort8v avv = *(const ushort8v*)&A[(size_t)ar * 128 + s * 32 + kb];
        if (AMODE == 0) {
            afrag[s] = __builtin_bit_cast(f16x8v, avv);
        } else if (AMODE == 1) {
            f16x8v o;
            #pragma unroll
            for (int j = 0; j < 8; ++j) {
                int qq = s * 32 + kb + j;
                o[j] = (_Float16)fmaxf(0.f, fmaf(h2f(avv[j]), C1[qq], D1[qq]));
            }
            afrag[s] = o;
        } else {
            ushort8v gv = *(const ushort8v*)&A2[(size_t)ar * 128 + s * 32 + kb];
            float sr = sN[ar], cr = cN[ar];
            f16x8v o;
            #pragma unroll
            for (int j = 0; j < 8; ++j) {
                int qq = s * 32 + kb + j;
                float y = h2f(avv[j]) * C1[qq] + D1[qq] + h2f(gv[j]) * C2[qq] + D2[qq]
                        + sr * AE[qq] + cr * BE[qq] + CE[qq];
                o[j] = (_Float16)fmaxf(0.f, y);
            }
            afrag[s] = o;
        }
    }
}

// ---------------------------------------------------------------------------
// Dual kernel: blocks [0,GB) node branch ZN = relu(bn(P))@WtZ + bZ;
// blocks [GB,2GB) FUSED gather+GEMM: As[r] = sum relu(bn(P[slot[r][j]])),
// Gh = As@WtG + deg*bG.  Gather goes straight to swizzled LDS A-tile.
// ---------------------------------------------------------------------------
__global__ __launch_bounds__(256) void dual_gemm_kernel(
    const unsigned* __restrict__ cnt, const int* __restrict__ slot,
    const unsigned short* __restrict__ Ph,
    const unsigned short* __restrict__ WtZ, const unsigned short* __restrict__ WtG,
    const float* __restrict__ bZ, const float* __restrict__ bG,
    const float* __restrict__ dg,
    const float* __restrict__ st1, const float* __restrict__ g1,
    const float* __restrict__ bt1,
    unsigned short* __restrict__ ZNh, unsigned short* __restrict__ Gh,
    float* __restrict__ statZN, float* __restrict__ statG)
{
    __shared__ __align__(16) unsigned short Bs[128 * 128];
    __shared__ __align__(16) unsigned short As[64 * 128];
    __shared__ float C1[128], D1[128];
    __shared__ float redS[4][128], redQ[4][128];
    const int t = threadIdx.x;
    const int b = blockIdx.x;

    bn_prep(st1, g1, bt1, C1, D1, t);
    __syncthreads();

    if (b < GB) {
        const int row0 = b * 64;
        stage_B(WtZ, Bs, t);
        f16x8v afrag[4];
        load_afrag_global<1>(row0, t, afrag, Ph, nullptr,
                             C1, D1, nullptr, nullptr, nullptr, nullptr, nullptr,
                             nullptr, nullptr);
        __syncthreads();   // Bs staged; A reads done
        gemm_core<false>(row0, t, b & (NSLICE - 1), afrag, bZ, nullptr,
                         ZNh, statZN, Bs, redS, redQ);
    } else {
        const int row0 = (b - GB) * 64;
        stage_B(WtG, Bs, t);
        // ---- fused gather into swizzled LDS A-tile
        const int w = t >> 6, lane = t & 63;
        const int q = lane >> 4, l16 = lane & 15;
        const int cb = l16 * 8;
        float av[8], bv[8];
        #pragma unroll
        for (int k = 0; k < 8; ++k) { av[k] = C1[cb + k]; bv[k] = D1[cb + k]; }
        #pragma unroll
        for (int i = 0; i < 4; ++i) {
            int nl = (w << 4) + i * 4 + q;           // local row 0..63
            int node = row0 + nl;
            int n = (int)cnt[node];
            n = n < CAP ? n : CAP;
            const int* sl = &slot[(size_t)node * CAP];
            float s0[8] = {0}, s1[8] = {0};
            int j = 0;
            for (; j + 1 < n; j += 2) {
                int r0 = sl[j], r1 = sl[j + 1];
                ushort8v v0 = *(const ushort8v*)&Ph[(size_t)r0 * 128 + cb];
                ushort8v v1 = *(const ushort8v*)&Ph[(size_t)r1 * 128 + cb];
                #pragma unroll
                for (int k = 0; k < 8; ++k) {
                    s0[k] += fmaxf(0.f, fmaf(h2f(v0[k]), av[k], bv[k]));
                    s1[k] += fmaxf(0.f, fmaf(h2f(v1[k]), av[k], bv[k]));
                }
            }
            if (j < n) {
                ushort8v v0 = *(const ushort8v*)&Ph[(size_t)sl[j] * 128 + cb];
                #pragma unroll
                for (int k = 0; k < 8; ++k)
                    s0[k] += fmaxf(0.f, fmaf(h2f(v0[k]), av[k], bv[k]));
            }
            ushort8v o;
            #pragma unroll
            for (int k = 0; k < 8; ++k) o[k] = f2h(s0[k] + s1[k]);
            *(ushort8v*)&As[(nl * 128 + cb) ^ ((nl & 7) << 3)] = o;
        }
        __syncthreads();   // As + Bs staged
        // ---- load afrag from LDS As (swizzled)
        const int la = lane & 15, lb = lane >> 4;
        const int arl = (w << 4) + la;
        const int abase = arl * 128 + lb * 8;
        const int aswz = (arl & 7) << 3;
        f16x8v afrag[4];
        #pragma unroll
        for (int s = 0; s < 4; ++s)
            afrag[s] = *(const f16x8v*)&As[(abase + (s << 5)) ^ aswz];
        gemm_core<true>(row0, t, b & (NSLICE - 1), afrag, bG, dg,
                        Gh, statG, Bs, redS, redQ);
    }
}

// ---------------------------------------------------------------------------
// Standalone GEMM (64-row tiles). grid GB x 256 thr.
// ---------------------------------------------------------------------------
template<int AMODE, bool RSC>
__global__ __launch_bounds__(256) void mfma_gemm_kernel(
    const unsigned short* __restrict__ A, const unsigned short* __restrict__ A2,
    const unsigned short* __restrict__ Wt,
    const float* __restrict__ bias, const float* __restrict__ rowscale,
    const float* __restrict__ st1, const float* __restrict__ g1, const float* __restrict__ bt1,
    const float* __restrict__ st2, const float* __restrict__ g2, const float* __restrict__ bt2,
    const float* __restrict__ sN, const float* __restrict__ cN,
    const float* __restrict__ scal,
    const float* __restrict__ We, const float* __restrict__ Be,
    const float* __restrict__ ge, const float* __restrict__ bte,
    unsigned short* __restrict__ Out, float* __restrict__ stats_out)
{
    __shared__ __align__(16) unsigned short Bs[128 * 128];
    __shared__ float C1[128], D1[128], C2[128], D2[128];
    __shared__ float AE[128], BE[128], CE[128];
    __shared__ float redS[4][128], redQ[4][128];
    const int t = threadIdx.x;

    if (AMODE >= 1) {
        bn_prep(st1, g1, bt1, C1, D1, t);
    }
    if (AMODE == 2) {
        bn_prep(st2, g2, bt2, C2, D2, t);
        if (t < 128) {
            float ms = scal[0] * RCP_N, vs = scal[1] * RCP_N - ms * ms;
            float mc = scal[2] * RCP_N, vc = scal[3] * RCP_N - mc * mc;
            float cov = scal[4] * RCP_N - ms * mc;
            float we = We[t], be = Be[t];
            float me = ms * we + mc * be;
            float ve = we * we * vs + be * be * vc + 2.f * we * be * cov;
            float ae = ge[t] * rsqrtf(ve + BN_EPS);
            AE[t] = we * ae; BE[t] = be * ae; CE[t] = bte[t] - me * ae;
        }
    }
    if (AMODE >= 1) __syncthreads();

    const int row0 = blockIdx.x * 64;
    stage_B(Wt, Bs, t);
    f16x8v afrag[4];
    load_afrag_global<AMODE>(row0, t, afrag, A, A2,
                             C1, D1, C2, D2, AE, BE, CE, sN, cN);
    // one barrier: Bs staged AND all A/A2 reads of this 64-row tile complete
    // (vmcnt drained before s_barrier) before in-place epilogue writes
    __syncthreads();
    gemm_core<RSC>(row0, t, blockIdx.x & (NSLICE - 1), afrag, bias, rowscale,
                   Out, stats_out, Bs, redS, redQ);
}

// Final elementwise: out(f32) = relu(bn(Z f16)), sliced stats input
__global__ __launch_bounds__(256) void bnrelu_kernel(
    const unsigned short* __restrict__ Z, const float* __restrict__ stz,
    const float* __restrict__ g, const float* __restrict__ bt,
    float* __restrict__ O)
{
    __shared__ float aT[128], bT[128];
    int t = threadIdx.x;
    bn_prep(stz, g, bt, aT, bT, t);
    __syncthreads();
    int stride = gridDim.x * 256;
    for (int idx = blockIdx.x * 256 + t; idx < N_NODES * 32; idx += stride) {
        int r = idx >> 5;
        int q = (idx & 31) * 4;
        ushort4 z = *(const ushort4*)&Z[(size_t)r * 128 + q];
        float4 o;
        o.x = fmaxf(0.f, fmaf(h2f(z.x), aT[q],     bT[q]));
        o.y = fmaxf(0.f, fmaf(h2f(z.y), aT[q + 1], bT[q + 1]));
        o.z = fmaxf(0.f, fmaf(h2f(z.z), aT[q + 2], bT[q + 2]));
        o.w = fmaxf(0.f, fmaf(h2f(z.w), aT[q + 3], bT[q + 3]));
        *(float4*)&O[(size_t)r * 128 + q] = o;
    }
}

// ---------------------------------------------------------------------------
extern "C" void kernel_launch(void* const* d_in, const int* in_sizes, int n_in,
                              void* d_out, int out_size, void* d_ws, size_t ws_size,
                              hipStream_t stream)
{
    const float* node_attr = (const float*)d_in[0];
    const int*   ei        = (const int*)d_in[1];
    const float* ea        = (const float*)d_in[2];
    const float* W0    = (const float*)d_in[3];
    const float* b0    = (const float*)d_in[4];
    const float* g0    = (const float*)d_in[5];
    const float* bt0   = (const float*)d_in[6];
    const float* Wnode = (const float*)d_in[7];
    const float* bnode = (const float*)d_in[8];
    const float* Wedge = (const float*)d_in[9];
    const float* bedge = (const float*)d_in[10];
    const float* Wnb   = (const float*)d_in[11];
    const float* bnb   = (const float*)d_in[12];
    const float* gn    = (const float*)d_in[13];
    const float* ge    = (const float*)d_in[14];
    const float* gnb   = (const float*)d_in[15];
    const float* gm1   = (const float*)d_in[16];
    const float* gm2   = (const float*)d_in[17];
    const float* btn   = (const float*)d_in[18];
    const float* bte   = (const float*)d_in[19];
    const float* btnb  = (const float*)d_in[20];
    const float* btm1  = (const float*)d_in[21];
    const float* btm2  = (const float*)d_in[22];
    const float* Wm1   = (const float*)d_in[23];
    const float* bm1   = (const float*)d_in[24];
    const float* Wm2   = (const float*)d_in[25];
    const float* bm2   = (const float*)d_in[26];
    float* out = (float*)d_out;

    // workspace: Ph|ZNh|Gh (f16, NF each) | sN|cN|dg (f32) | st(sliced stats)
    //            | scP(u64,N) | cursor(u32,N) | slot(int, N*CAP) | Wtb(f16)
    unsigned short* Ph  = (unsigned short*)d_ws;
    unsigned short* ZNh = Ph + NF;
    unsigned short* Gh  = ZNh + NF;
    float* sN = (float*)(Gh + NF);
    float* cN = sN + N_NODES;
    float* dg = cN + N_NODES;
    float* st = dg + N_NODES;
    // st layout: [0..4] moments | [256..256+STB) init stats |
    //            layer i stat j at 256+STB + (i*4+j)*STB  (j: zn,aggr,z1,z2)
    const size_t ST_FLOATS = 256 + (size_t)STB * 13;
    unsigned long long* scP = (unsigned long long*)(st + ST_FLOATS);
    unsigned* cursor = (unsigned*)(scP + N_NODES);
    int* slot = (int*)(cursor + N_NODES);
    unsigned short* Wtb = (unsigned short*)(slot + (size_t)N_NODES * CAP);
    float* stInit = st + 256;
    float* layBase = st + 256 + STB;

    // zero st | scP | cursor (contiguous)
    (void)hipMemsetAsync(st, 0, (ST_FLOATS + 3 * (size_t)N_NODES) * sizeof(float), stream);
    wprep_kernel<<<48, 256, 0, stream>>>(Wnode, Wnb, Wm1, Wm2, Wtb);
    edge_init_kernel<<<3125, 256, 0, stream>>>(
        node_attr, W0, b0, Ph, stInit, ei, ea, scP, cursor, slot);
    decode_kernel<<<157, 256, 0, stream>>>(scP, cursor, sN, cN, dg, st);

    const float* xst = stInit;
    const float* xg  = g0;
    const float* xbt = bt0;

    for (int i = 0; i < 3; ++i) {
        float* lay = layBase + (size_t)i * 4 * STB;
        // dual: ZN = relu(bn(P)) @ Wnode + bnode  ||  Gh = gather(P) @ Wnb + deg*bnb
        dual_gemm_kernel<<<2 * GB, 256, 0, stream>>>(
            cursor, slot, Ph,
            Wtb + (size_t)(0 + i) * 16384, Wtb + (size_t)(3 + i) * 16384,
            bnode + i * 128, bnb + i * 128, dg,
            xst, xg, xbt,
            ZNh, Gh, lay, lay + STB);
        // z1 = relu(bn(ZN)+bn(G)+ea) @ Wm1 + bm1 (+stats) -> ZN (fused combine)
        mfma_gemm_kernel<2, false><<<GB, 256, 0, stream>>>(
            ZNh, Gh, Wtb + (size_t)(6 + i) * 16384, bm1 + i * 128, nullptr,
            lay, gn + i * 128, btn + i * 128,
            lay + STB, gnb + i * 128, btnb + i * 128,
            sN, cN, st,
            Wedge + i * 128, bedge + i * 128, ge + i * 128, bte + i * 128,
            ZNh, lay + 2 * STB);
        // z2 = relu(bn(z1)) @ Wm2 + bm2 (+stats) -> P
        mfma_gemm_kernel<1, false><<<GB, 256, 0, stream>>>(
            ZNh, nullptr, Wtb + (size_t)(9 + i) * 16384, bm2 + i * 128, nullptr,
            lay + 2 * STB, gm1 + i * 128, btm1 + i * 128, nullptr, nullptr, nullptr,
            nullptr, nullptr, nullptr, nullptr, nullptr, nullptr, nullptr,
            Ph, lay + 3 * STB);

        xst = lay + 3 * STB;
        xg  = gm2 + i * 128;
        xbt = btm2 + i * 128;
    }
    bnrelu_kernel<<<2048, 256, 0, stream>>>(Ph, xst, xg, xbt, out);
}

// Round 14
// 347.855 us; speedup vs baseline: 1.2490x; 1.2490x over previous
//
#include <hip/hip_runtime.h>

#define N_NODES 40000
#define N_EDGES 640000
#define EMB 128
#define NF ((size_t)N_NODES * EMB)
#define RCP_N (1.0f / (float)N_NODES)
#define BN_EPS 1e-5f
#define CAP 64          // fixed bucket capacity (avg deg 16; P(>64) ~ 1e-18)
#define NSLICE 16       // stats accumulator slices (atomic contention fix)
#define STB (NSLICE * 256)   // floats per sliced stat block
#define GB 625          // GEMM grid: 64-row tiles, 256 threads

typedef _Float16 f16x8v __attribute__((ext_vector_type(8)));
typedef float f32x4v __attribute__((ext_vector_type(4)));
typedef unsigned short ushort8v __attribute__((ext_vector_type(8)));

__device__ __forceinline__ unsigned short f2h(float v) {
    return __builtin_bit_cast(unsigned short, (_Float16)v);
}
__device__ __forceinline__ float h2f(unsigned short u) {
    return (float)__builtin_bit_cast(_Float16, u);
}

// Sum NSLICE slices of a stat block -> bn scale/shift (threads t<128)
__device__ __forceinline__ void bn_prep(
    const float* __restrict__ stat, const float* __restrict__ g,
    const float* __restrict__ bt, float* C, float* D, int t)
{
    if (t < 128) {
        float sm = 0.f, sq = 0.f;
        #pragma unroll
        for (int s = 0; s < NSLICE; ++s) {
            sm += stat[s * 256 + t];
            sq += stat[s * 256 + 128 + t];
        }
        float m = sm * RCP_N;
        float v = sq * RCP_N - m * m;
        float a = g[t] * rsqrtf(v + BN_EPS);
        C[t] = a; D[t] = bt[t] - m * a;
    }
}

// ---------------------------------------------------------------------------
// Merged edge pass + initial node MLP (tiny LDS so edge occupancy unhurt):
//   blocks [0,625): P(f16) = node_attr @ W0 + b0, sliced col stats
//   blocks [625,3125): per-edge atomics (1 edge/thread = max outstanding)
// ---------------------------------------------------------------------------
__global__ __launch_bounds__(256) void edge_init_kernel(
    const float* __restrict__ na, const float* __restrict__ W0,
    const float* __restrict__ b0, unsigned short* __restrict__ Z,
    float* __restrict__ st,
    const int* __restrict__ ei, const float* __restrict__ ea,
    unsigned long long* __restrict__ scP, unsigned* __restrict__ cursor,
    int* __restrict__ slot)
{
    __shared__ float red[256];
    const int blk = blockIdx.x;
    const int t = threadIdx.x;
    if (blk < 625) {
        int col = t & 127, rh = t >> 7;
        float w0 = W0[col], w1 = W0[128 + col], bb = b0[col];
        int rbase = blk * 64;
        float sm = 0.f, sq = 0.f;
        #pragma unroll 4
        for (int i = 0; i < 32; ++i) {
            int r = rbase + rh + i * 2;
            float2 nv = *(const float2*)&na[r * 2];
            float v = fmaf(nv.x, w0, fmaf(nv.y, w1, bb));
            Z[(size_t)r * 128 + col] = f2h(v);
            sm += v; sq += v * v;
        }
        float* stS = st + (blk & (NSLICE - 1)) * 256;
        red[t] = sm; __syncthreads();
        if (t < 128) atomicAdd(&stS[t], red[t] + red[t + 128]);
        __syncthreads();
        red[t] = sq; __syncthreads();
        if (t < 128) atomicAdd(&stS[128 + t], red[t] + red[t + 128]);
    } else {
        int e = (blk - 625) * 256 + t;     // 2500*256 == N_EDGES
        int r = ei[e];
        int d = ei[N_EDGES + e];
        int fx = (int)rintf(ea[e] * 65536.0f);
        unsigned long long add =
            (((unsigned long long)(unsigned)(fx + 0x40000000)) << 20) | 1ULL;
        atomicAdd(&scP[r], add);
        unsigned pos = atomicAdd(&cursor[d], 1u);
        slot[(size_t)d * CAP + (pos < CAP ? pos : CAP - 1)] = r;
    }
}

// Decode scP -> sN, cN + scalar moments; cursor -> f32 deg.  grid 157
__global__ __launch_bounds__(256) void decode_kernel(
    const unsigned long long* __restrict__ scP, const unsigned* __restrict__ cursor,
    float* __restrict__ sN, float* __restrict__ cN, float* __restrict__ dgf,
    float* __restrict__ mom)
{
    int t = threadIdx.x;
    int i = blockIdx.x * 256 + t;
    float a0 = 0.f, a1 = 0.f, a2 = 0.f, a3 = 0.f, a4 = 0.f;
    if (i < N_NODES) {
        unsigned long long v = scP[i];
        unsigned cnt = (unsigned)(v & 0xFFFFFULL);
        long long sp = (long long)(v >> 20) - ((long long)cnt << 30);
        float s = (float)sp * (1.0f / 65536.0f);
        float c = (float)cnt;
        sN[i] = s; cN[i] = c;
        dgf[i] = (float)cursor[i];
        a0 = s; a1 = s * s; a2 = c; a3 = c * c; a4 = s * c;
    }
    #pragma unroll
    for (int off = 32; off > 0; off >>= 1) {
        a0 += __shfl_down(a0, off);
        a1 += __shfl_down(a1, off);
        a2 += __shfl_down(a2, off);
        a3 += __shfl_down(a3, off);
        a4 += __shfl_down(a4, off);
    }
    if ((t & 63) == 0) {
        atomicAdd(&mom[0], a0);
        atomicAdd(&mom[1], a1);
        atomicAdd(&mom[2], a2);
        atomicAdd(&mom[3], a3);
        atomicAdd(&mom[4], a4);
    }
}

// ---------------------------------------------------------------------------
// Weight prep: Wt[mat][n][k] = f16(W[mat][k][n]), 12 matrices of 128x128.
// ---------------------------------------------------------------------------
__global__ __launch_bounds__(256) void wprep_kernel(
    const float* __restrict__ Wnode, const float* __restrict__ Wnb,
    const float* __restrict__ Wm1, const float* __restrict__ Wm2,
    unsigned short* __restrict__ Wt)
{
    __shared__ float tile[32][129];
    int b = blockIdx.x;
    int mat = b >> 2, kc = (b & 3) * 32;
    int grp = mat / 3, lay = mat % 3;
    const float* src = (grp == 0) ? Wnode : (grp == 1) ? Wnb : (grp == 2) ? Wm1 : Wm2;
    src += (size_t)lay * 16384;
    int t = threadIdx.x;
    #pragma unroll
    for (int i = 0; i < 16; ++i) {
        int idx = t + i * 256;
        int r = idx >> 7, n = idx & 127;
        tile[r][n] = src[(size_t)(kc + r) * 128 + n];
    }
    __syncthreads();
    int n = t >> 1, h = (t & 1) * 16;
    ushort8v o0, o1;
    #pragma unroll
    for (int j = 0; j < 8; ++j) o0[j] = f2h(tile[h + j][n]);
    #pragma unroll
    for (int j = 0; j < 8; ++j) o1[j] = f2h(tile[h + 8 + j][n]);
    unsigned short* dst = &Wt[(size_t)mat * 16384 + n * 128 + kc + h];
    *(ushort8v*)dst = o0;
    *(ushort8v*)(dst + 8) = o1;
}

// ---------------------------------------------------------------------------
// Gather with inline bn+relu: G[d] = sum relu(a*P[slot[d][j]]+b)
// Quarter-wave (16 lanes x 16B = one 256B row) per row; 4-deep unroll
// (slots j, j+4, j+8, j+12) = 4 row-loads in flight per thread — covers
// the avg-degree-16 node in ONE iteration.
// ---------------------------------------------------------------------------
__global__ __launch_bounds__(256) void gather_bn_kernel(
    const unsigned* __restrict__ cnt, const int* __restrict__ slot,
    const unsigned short* __restrict__ Ph,
    const float* __restrict__ stat, const float* __restrict__ g_in,
    const float* __restrict__ bt_in,
    unsigned short* __restrict__ Gh)
{
    __shared__ float aT[128], bT[128];
    int t = threadIdx.x;
    bn_prep(stat, g_in, bt_in, aT, bT, t);
    __syncthreads();
    int wid = (blockIdx.x * 256 + t) >> 6;   // grid 10000 -> 40000 waves
    int lane = t & 63;
    int q = lane >> 4, l16 = lane & 15;
    int cb = l16 * 8;
    float av[8], bv[8];
    #pragma unroll
    for (int k = 0; k < 8; ++k) { av[k] = aT[cb + k]; bv[k] = bT[cb + k]; }
    int n = (int)cnt[wid];
    n = n < CAP ? n : CAP;
    const int* sl = &slot[(size_t)wid * CAP];
    float s0[8] = {0}, s1[8] = {0}, s2[8] = {0}, s3[8] = {0};
    int j = q;
    for (; j + 12 < n; j += 16) {
        int r0 = sl[j], r1 = sl[j + 4], r2 = sl[j + 8], r3 = sl[j + 12];
        ushort8v v0 = *(const ushort8v*)&Ph[(size_t)r0 * 128 + cb];
        ushort8v v1 = *(const ushort8v*)&Ph[(size_t)r1 * 128 + cb];
        ushort8v v2 = *(const ushort8v*)&Ph[(size_t)r2 * 128 + cb];
        ushort8v v3 = *(const ushort8v*)&Ph[(size_t)r3 * 128 + cb];
        #pragma unroll
        for (int k = 0; k < 8; ++k) {
            s0[k] += fmaxf(0.f, fmaf(h2f(v0[k]), av[k], bv[k]));
            s1[k] += fmaxf(0.f, fmaf(h2f(v1[k]), av[k], bv[k]));
            s2[k] += fmaxf(0.f, fmaf(h2f(v2[k]), av[k], bv[k]));
            s3[k] += fmaxf(0.f, fmaf(h2f(v3[k]), av[k], bv[k]));
        }
    }
    for (; j < n; j += 4) {
        int r0 = sl[j];
        ushort8v v0 = *(const ushort8v*)&Ph[(size_t)r0 * 128 + cb];
        #pragma unroll
        for (int k = 0; k < 8; ++k)
            s0[k] += fmaxf(0.f, fmaf(h2f(v0[k]), av[k], bv[k]));
    }
    #pragma unroll
    for (int k = 0; k < 8; ++k) {
        float v = (s0[k] + s1[k]) + (s2[k] + s3[k]);
        v += __shfl_xor(v, 16);
        v += __shfl_xor(v, 32);
        s0[k] = v;
    }
    if (q == 0) {
        ushort8v o;
        #pragma unroll
        for (int k = 0; k < 8; ++k) o[k] = f2h(s0[k]);
        *(ushort8v*)&Gh[(size_t)wid * 128 + cb] = o;
    }
}

// ---------------------------------------------------------------------------
// GEMM core: MFMA from afrag (regs) + swizzled LDS B, epilogue with bias,
// f16 write, sliced stats.  wave = 16 rows x 128 cols, 4 waves = 64 rows.
// ---------------------------------------------------------------------------
template<bool RSC>
__device__ __forceinline__ void gemm_core(
    int row0, int t, int slice, f16x8v afrag[4],
    const float* __restrict__ bias, const float* __restrict__ rowscale,
    unsigned short* __restrict__ Out, float* __restrict__ stats_out,
    const unsigned short* Bs, float (*redS)[128], float (*redQ)[128])
{
    const int w = t >> 6, lane = t & 63;
    const int la = lane & 15, lb = lane >> 4;
    const int kb = lb * 8;

    f32x4v acc[8];
    #pragma unroll
    for (int c = 0; c < 8; ++c) acc[c] = (f32x4v){0.f, 0.f, 0.f, 0.f};

    #pragma unroll
    for (int c = 0; c < 8; ++c) {
        int bn_ = (c << 4) + la;
        int bbase = bn_ * 128;
        int bswz = (bn_ & 7) << 3;
        #pragma unroll
        for (int s = 0; s < 4; ++s) {
            f16x8v bf = *(const f16x8v*)&Bs[(bbase + s * 32 + kb) ^ bswz];
            acc[c] = __builtin_amdgcn_mfma_f32_16x16x32_f16(
                afrag[s], bf, acc[c], 0, 0, 0);
        }
    }

    const int orow0 = row0 + (w << 4) + lb * 4;
    float rsj[4];
    if (RSC) {
        #pragma unroll
        for (int j = 0; j < 4; ++j) rsj[j] = rowscale[orow0 + j];
    }
    float csum[8], csq[8];
    #pragma unroll
    for (int c = 0; c < 8; ++c) {
        int col = (c << 4) + la;
        float bc = bias[col];
        float s0 = 0.f, s1 = 0.f;
        #pragma unroll
        for (int j = 0; j < 4; ++j) {
            float v = acc[c][j] + (RSC ? rsj[j] * bc : bc);
            Out[(size_t)(orow0 + j) * 128 + col] = f2h(v);
            s0 += v; s1 += v * v;
        }
        csum[c] = s0; csq[c] = s1;
    }
    #pragma unroll
    for (int c = 0; c < 8; ++c) {
        csum[c] += __shfl_xor(csum[c], 16);
        csum[c] += __shfl_xor(csum[c], 32);
        csq[c]  += __shfl_xor(csq[c], 16);
        csq[c]  += __shfl_xor(csq[c], 32);
    }
    if (lane < 16) {
        #pragma unroll
        for (int c = 0; c < 8; ++c) {
            redS[w][(c << 4) + lane] = csum[c];
            redQ[w][(c << 4) + lane] = csq[c];
        }
    }
    __syncthreads();
    float* stS = stats_out + slice * 256;
    if (t < 128) {
        atomicAdd(&stS[t], redS[0][t] + redS[1][t] + redS[2][t] + redS[3][t]);
        atomicAdd(&stS[128 + t], redQ[0][t] + redQ[1][t] + redQ[2][t] + redQ[3][t]);
    }
}

// Stage B (128x128 f16) into LDS with XOR swizzle (R5-proven pattern)
__device__ __forceinline__ void stage_B(
    const unsigned short* __restrict__ Wt, unsigned short* Bs, int t)
{
    #pragma unroll
    for (int i = 0; i < 8; ++i) {
        int cch = t + i * 256;
        int n = cch >> 4, off = (cch & 15) << 3;
        ushort8v w = *(const ushort8v*)&Wt[n * 128 + off];
        *(ushort8v*)&Bs[(n * 128 + off) ^ ((n & 7) << 3)] = w;
    }
}

// Load afrag from global A with optional transforms (AMODE 0/1/2)
template<int AMODE>
__device__ __forceinline__ void load_afrag_global(
    int row0, int t, f16x8v afrag[4],
    const unsigned short* __restrict__ A, const unsigned short* __restrict__ A2,
    const float* C1, const float* D1, const float* C2, const float* D2,
    const float* AE, const float* BE, const float* CE,
    const float* __restrict__ sN, const float* __restrict__ cN)
{
    const int w = t >> 6, lane = t & 63;
    const int la = lane & 15, lb = lane >> 4;
    const int ar = row0 + (w << 4) + la;
    const int kb = lb * 8;
    #pragma unroll
    for (int s = 0; s < 4; ++s) {
        ushort8v avv = *(const ushort8v*)&A[(size_t)ar * 128 + s * 32 + kb];
        if (AMODE == 0) {
            afrag[s] = __builtin_bit_cast(f16x8v, avv);
        } else if (AMODE == 1) {
            f16x8v o;
            #pragma unroll
            for (int j = 0; j < 8; ++j) {
                int qq = s * 32 + kb + j;
                o[j] = (_Float16)fmaxf(0.f, fmaf(h2f(avv[j]), C1[qq], D1[qq]));
            }
            afrag[s] = o;
        } else {
            ushort8v gv = *(const ushort8v*)&A2[(size_t)ar * 128 + s * 32 + kb];
            float sr = sN[ar], cr = cN[ar];
            f16x8v o;
            #pragma unroll
            for (int j = 0; j < 8; ++j) {
                int qq = s * 32 + kb + j;
                float y = h2f(avv[j]) * C1[qq] + D1[qq] + h2f(gv[j]) * C2[qq] + D2[qq]
                        + sr * AE[qq] + cr * BE[qq] + CE[qq];
                o[j] = (_Float16)fmaxf(0.f, y);
            }
            afrag[s] = o;
        }
    }
}

// ---------------------------------------------------------------------------
// Dual GEMM: blocks [0,GB) node branch (AMODE1), [GB,2GB) neighbor (AMODE0+RSC)
// ---------------------------------------------------------------------------
__global__ __launch_bounds__(256) void dual_gemm_kernel(
    const unsigned short* __restrict__ Ph, unsigned short* __restrict__ Gh,
    const unsigned short* __restrict__ WtZ, const unsigned short* __restrict__ WtG,
    const float* __restrict__ bZ, const float* __restrict__ bG,
    const float* __restrict__ dg,
    const float* __restrict__ st1, const float* __restrict__ g1,
    const float* __restrict__ bt1,
    unsigned short* __restrict__ ZNh,
    float* __restrict__ statZN, float* __restrict__ statG)
{
    __shared__ __align__(16) unsigned short Bs[128 * 128];
    __shared__ float C1[128], D1[128];
    __shared__ float redS[4][128], redQ[4][128];
    const int t = threadIdx.x;
    const int b = blockIdx.x;

    if (b < GB) {
        bn_prep(st1, g1, bt1, C1, D1, t);
        __syncthreads();
        const int row0 = b * 64;
        stage_B(WtZ, Bs, t);
        f16x8v afrag[4];
        load_afrag_global<1>(row0, t, afrag, Ph, nullptr,
                             C1, D1, nullptr, nullptr, nullptr, nullptr, nullptr,
                             nullptr, nullptr);
        __syncthreads();   // Bs staged; A reads done
        gemm_core<false>(row0, t, b & (NSLICE - 1), afrag, bZ, nullptr,
                         ZNh, statZN, Bs, redS, redQ);
    } else {
        const int row0 = (b - GB) * 64;
        stage_B(WtG, Bs, t);
        f16x8v afrag[4];
        load_afrag_global<0>(row0, t, afrag, Gh, nullptr,
                             nullptr, nullptr, nullptr, nullptr, nullptr,
                             nullptr, nullptr, nullptr, nullptr);
        __syncthreads();   // Bs staged; A reads done (in-place safe)
        gemm_core<true>(row0, t, b & (NSLICE - 1), afrag, bG, dg,
                        Gh, statG, Bs, redS, redQ);
    }
}

// ---------------------------------------------------------------------------
// Standalone GEMM (64-row tiles). grid GB x 256 thr.
// ---------------------------------------------------------------------------
template<int AMODE, bool RSC>
__global__ __launch_bounds__(256) void mfma_gemm_kernel(
    const unsigned short* __restrict__ A, const unsigned short* __restrict__ A2,
    const unsigned short* __restrict__ Wt,
    const float* __restrict__ bias, const float* __restrict__ rowscale,
    const float* __restrict__ st1, const float* __restrict__ g1, const float* __restrict__ bt1,
    const float* __restrict__ st2, const float* __restrict__ g2, const float* __restrict__ bt2,
    const float* __restrict__ sN, const float* __restrict__ cN,
    const float* __restrict__ scal,
    const float* __restrict__ We, const float* __restrict__ Be,
    const float* __restrict__ ge, const float* __restrict__ bte,
    unsigned short* __restrict__ Out, float* __restrict__ stats_out)
{
    __shared__ __align__(16) unsigned short Bs[128 * 128];
    __shared__ float C1[128], D1[128], C2[128], D2[128];
    __shared__ float AE[128], BE[128], CE[128];
    __shared__ float redS[4][128], redQ[4][128];
    const int t = threadIdx.x;

    if (AMODE >= 1) {
        bn_prep(st1, g1, bt1, C1, D1, t);
    }
    if (AMODE == 2) {
        bn_prep(st2, g2, bt2, C2, D2, t);
        if (t < 128) {
            float ms = scal[0] * RCP_N, vs = scal[1] * RCP_N - ms * ms;
            float mc = scal[2] * RCP_N, vc = scal[3] * RCP_N - mc * mc;
            float cov = scal[4] * RCP_N - ms * mc;
            float we = We[t], be = Be[t];
            float me = ms * we + mc * be;
            float ve = we * we * vs + be * be * vc + 2.f * we * be * cov;
            float ae = ge[t] * rsqrtf(ve + BN_EPS);
            AE[t] = we * ae; BE[t] = be * ae; CE[t] = bte[t] - me * ae;
        }
    }
    if (AMODE >= 1) __syncthreads();

    const int row0 = blockIdx.x * 64;
    stage_B(Wt, Bs, t);
    f16x8v afrag[4];
    load_afrag_global<AMODE>(row0, t, afrag, A, A2,
                             C1, D1, C2, D2, AE, BE, CE, sN, cN);
    // one barrier: Bs staged AND all A/A2 reads of this 64-row tile complete
    // (vmcnt drained before s_barrier) before in-place epilogue writes
    __syncthreads();
    gemm_core<RSC>(row0, t, blockIdx.x & (NSLICE - 1), afrag, bias, rowscale,
                   Out, stats_out, Bs, redS, redQ);
}

// Final elementwise: out(f32) = relu(bn(Z f16)), sliced stats input
__global__ __launch_bounds__(256) void bnrelu_kernel(
    const unsigned short* __restrict__ Z, const float* __restrict__ stz,
    const float* __restrict__ g, const float* __restrict__ bt,
    float* __restrict__ O)
{
    __shared__ float aT[128], bT[128];
    int t = threadIdx.x;
    bn_prep(stz, g, bt, aT, bT, t);
    __syncthreads();
    int stride = gridDim.x * 256;
    for (int idx = blockIdx.x * 256 + t; idx < N_NODES * 32; idx += stride) {
        int r = idx >> 5;
        int q = (idx & 31) * 4;
        ushort4 z = *(const ushort4*)&Z[(size_t)r * 128 + q];
        float4 o;
        o.x = fmaxf(0.f, fmaf(h2f(z.x), aT[q],     bT[q]));
        o.y = fmaxf(0.f, fmaf(h2f(z.y), aT[q + 1], bT[q + 1]));
        o.z = fmaxf(0.f, fmaf(h2f(z.z), aT[q + 2], bT[q + 2]));
        o.w = fmaxf(0.f, fmaf(h2f(z.w), aT[q + 3], bT[q + 3]));
        *(float4*)&O[(size_t)r * 128 + q] = o;
    }
}

// ---------------------------------------------------------------------------
extern "C" void kernel_launch(void* const* d_in, const int* in_sizes, int n_in,
                              void* d_out, int out_size, void* d_ws, size_t ws_size,
                              hipStream_t stream)
{
    const float* node_attr = (const float*)d_in[0];
    const int*   ei        = (const int*)d_in[1];
    const float* ea        = (const float*)d_in[2];
    const float* W0    = (const float*)d_in[3];
    const float* b0    = (const float*)d_in[4];
    const float* g0    = (const float*)d_in[5];
    const float* bt0   = (const float*)d_in[6];
    const float* Wnode = (const float*)d_in[7];
    const float* bnode = (const float*)d_in[8];
    const float* Wedge = (const float*)d_in[9];
    const float* bedge = (const float*)d_in[10];
    const float* Wnb   = (const float*)d_in[11];
    const float* bnb   = (const float*)d_in[12];
    const float* gn    = (const float*)d_in[13];
    const float* ge    = (const float*)d_in[14];
    const float* gnb   = (const float*)d_in[15];
    const float* gm1   = (const float*)d_in[16];
    const float* gm2   = (const float*)d_in[17];
    const float* btn   = (const float*)d_in[18];
    const float* bte   = (const float*)d_in[19];
    const float* btnb  = (const float*)d_in[20];
    const float* btm1  = (const float*)d_in[21];
    const float* btm2  = (const float*)d_in[22];
    const float* Wm1   = (const float*)d_in[23];
    const float* bm1   = (const float*)d_in[24];
    const float* Wm2   = (const float*)d_in[25];
    const float* bm2   = (const float*)d_in[26];
    float* out = (float*)d_out;

    // workspace: Ph|ZNh|Gh (f16, NF each) | sN|cN|dg (f32) | st(sliced stats)
    //            | scP(u64,N) | cursor(u32,N) | slot(int, N*CAP) | Wtb(f16)
    unsigned short* Ph  = (unsigned short*)d_ws;
    unsigned short* ZNh = Ph + NF;
    unsigned short* Gh  = ZNh + NF;
    float* sN = (float*)(Gh + NF);
    float* cN = sN + N_NODES;
    float* dg = cN + N_NODES;
    float* st = dg + N_NODES;
    // st layout: [0..4] moments | [256..256+STB) init stats |
    //            layer i stat j at 256+STB + (i*4+j)*STB  (j: zn,aggr,z1,z2)
    const size_t ST_FLOATS = 256 + (size_t)STB * 13;
    unsigned long long* scP = (unsigned long long*)(st + ST_FLOATS);
    unsigned* cursor = (unsigned*)(scP + N_NODES);
    int* slot = (int*)(cursor + N_NODES);
    unsigned short* Wtb = (unsigned short*)(slot + (size_t)N_NODES * CAP);
    float* stInit = st + 256;
    float* layBase = st + 256 + STB;

    // zero st | scP | cursor (contiguous)
    (void)hipMemsetAsync(st, 0, (ST_FLOATS + 3 * (size_t)N_NODES) * sizeof(float), stream);
    wprep_kernel<<<48, 256, 0, stream>>>(Wnode, Wnb, Wm1, Wm2, Wtb);
    edge_init_kernel<<<3125, 256, 0, stream>>>(
        node_attr, W0, b0, Ph, stInit, ei, ea, scP, cursor, slot);
    decode_kernel<<<157, 256, 0, stream>>>(scP, cursor, sN, cN, dg, st);

    const float* xst = stInit;
    const float* xg  = g0;
    const float* xbt = bt0;

    for (int i = 0; i < 3; ++i) {
        float* lay = layBase + (size_t)i * 4 * STB;
        // G = sum over in-neighbors of relu(bn(P[src]))
        gather_bn_kernel<<<10000, 256, 0, stream>>>(cursor, slot, Ph, xst, xg, xbt, Gh);
        // dual: ZN = relu(bn(P)) @ Wnode + bnode  ||  G = G @ Wnb + deg*bnb
        dual_gemm_kernel<<<2 * GB, 256, 0, stream>>>(
            Ph, Gh,
            Wtb + (size_t)(0 + i) * 16384, Wtb + (size_t)(3 + i) * 16384,
            bnode + i * 128, bnb + i * 128, dg,
            xst, xg, xbt,
            ZNh, lay, lay + STB);
        // z1 = relu(bn(ZN)+bn(G)+ea) @ Wm1 + bm1 (+stats) -> ZN (fused combine)
        mfma_gemm_kernel<2, false><<<GB, 256, 0, stream>>>(
            ZNh, Gh, Wtb + (size_t)(6 + i) * 16384, bm1 + i * 128, nullptr,
            lay, gn + i * 128, btn + i * 128,
            lay + STB, gnb + i * 128, btnb + i * 128,
            sN, cN, st,
            Wedge + i * 128, bedge + i * 128, ge + i * 128, bte + i * 128,
            ZNh, lay + 2 * STB);
        // z2 = relu(bn(z1)) @ Wm2 + bm2 (+stats) -> P
        mfma_gemm_kernel<1, false><<<GB, 256, 0, stream>>>(
            ZNh, nullptr, Wtb + (size_t)(9 + i) * 16384, bm2 + i * 128, nullptr,
            lay + 2 * STB, gm1 + i * 128, btm1 + i * 128, nullptr, nullptr, nullptr,
            nullptr, nullptr, nullptr, nullptr, nullptr, nullptr, nullptr,
            Ph, lay + 3 * STB);

        xst = lay + 3 * STB;
        xg  = gm2 + i * 128;
        xbt = btm2 + i * 128;
    }
    bnrelu_kernel<<<2048, 256, 0, stream>>>(Ph, xst, xg, xbt, out);
}

// Round 15
// 308.859 us; speedup vs baseline: 1.4067x; 1.1263x over previous
//
#include <hip/hip_runtime.h>

#define N_NODES 40000
#define N_EDGES 640000
#define EMB 128
#define NF ((size_t)N_NODES * EMB)
#define RCP_N (1.0f / (float)N_NODES)
#define BN_EPS 1e-5f
#define CAP 64          // fixed bucket capacity (avg deg 16; P(>64) ~ 1e-18)
#define NSLICE 16       // stats accumulator slices (atomic contention fix)
#define STB (NSLICE * 256)   // floats per sliced stat block
#define GB 625          // GEMM grid: 64-row tiles, 256 threads

typedef _Float16 f16x8v __attribute__((ext_vector_type(8)));
typedef float f32x4v __attribute__((ext_vector_type(4)));
typedef unsigned short ushort8v __attribute__((ext_vector_type(8)));

__device__ __forceinline__ unsigned short f2h(float v) {
    return __builtin_bit_cast(unsigned short, (_Float16)v);
}
__device__ __forceinline__ float h2f(unsigned short u) {
    return (float)__builtin_bit_cast(_Float16, u);
}

// Sum NSLICE slices of a stat block -> bn scale/shift (threads t<128)
__device__ __forceinline__ void bn_prep(
    const float* __restrict__ stat, const float* __restrict__ g,
    const float* __restrict__ bt, float* C, float* D, int t)
{
    if (t < 128) {
        float sm = 0.f, sq = 0.f;
        #pragma unroll
        for (int s = 0; s < NSLICE; ++s) {
            sm += stat[s * 256 + t];
            sq += stat[s * 256 + 128 + t];
        }
        float m = sm * RCP_N;
        float v = sq * RCP_N - m * m;
        float a = g[t] * rsqrtf(v + BN_EPS);
        C[t] = a; D[t] = bt[t] - m * a;
    }
}

// ---------------------------------------------------------------------------
// Merged edge pass + initial node MLP + LDS-free weight prep:
//   blocks [0,625): P(f16) = node_attr @ W0 + b0, sliced col stats
//   blocks [625,3125): per-edge atomics (1 edge/thread = max outstanding)
//   blocks [3125,3221): Wt[mat][n][k] = f16(W[mat][k][n]) (no LDS)
// ---------------------------------------------------------------------------
__global__ __launch_bounds__(256) void edge_init_kernel(
    const float* __restrict__ na, const float* __restrict__ W0,
    const float* __restrict__ b0, unsigned short* __restrict__ Z,
    float* __restrict__ st,
    const int* __restrict__ ei, const float* __restrict__ ea,
    unsigned long long* __restrict__ scP, unsigned* __restrict__ cursor,
    unsigned short* __restrict__ slot,
    const float* __restrict__ Wnode, const float* __restrict__ Wnb,
    const float* __restrict__ Wm1, const float* __restrict__ Wm2,
    unsigned short* __restrict__ Wt)
{
    __shared__ float red[256];
    const int blk = blockIdx.x;
    const int t = threadIdx.x;
    if (blk < 625) {
        int col = t & 127, rh = t >> 7;
        float w0 = W0[col], w1 = W0[128 + col], bb = b0[col];
        int rbase = blk * 64;
        float sm = 0.f, sq = 0.f;
        #pragma unroll 4
        for (int i = 0; i < 32; ++i) {
            int r = rbase + rh + i * 2;
            float2 nv = *(const float2*)&na[r * 2];
            float v = fmaf(nv.x, w0, fmaf(nv.y, w1, bb));
            Z[(size_t)r * 128 + col] = f2h(v);
            sm += v; sq += v * v;
        }
        float* stS = st + (blk & (NSLICE - 1)) * 256;
        red[t] = sm; __syncthreads();
        if (t < 128) atomicAdd(&stS[t], red[t] + red[t + 128]);
        __syncthreads();
        red[t] = sq; __syncthreads();
        if (t < 128) atomicAdd(&stS[128 + t], red[t] + red[t + 128]);
    } else if (blk < 3125) {
        int e = (blk - 625) * 256 + t;     // 2500*256 == N_EDGES
        int r = ei[e];
        int d = ei[N_EDGES + e];
        int fx = (int)rintf(ea[e] * 65536.0f);
        unsigned long long add =
            (((unsigned long long)(unsigned)(fx + 0x40000000)) << 20) | 1ULL;
        atomicAdd(&scP[r], add);
        unsigned pos = atomicAdd(&cursor[d], 1u);
        slot[(size_t)d * CAP + (pos < CAP ? pos : CAP - 1)] = (unsigned short)r;
    } else {
        // LDS-free weight transpose: idx -> matrix, 2048 vec8 outputs/matrix
        int idx = blk - 3125;              // 0..95, 8 blocks per matrix
        int mat = idx >> 3;
        int v = (idx & 7) * 256 + t;       // 0..2047
        int kb = (v >> 7) * 8;             // 0,8,...,120
        int n = v & 127;
        int grp = mat / 3, lay = mat % 3;
        const float* src = (grp == 0) ? Wnode : (grp == 1) ? Wnb
                         : (grp == 2) ? Wm1 : Wm2;
        src += (size_t)lay * 16384;
        ushort8v o;
        #pragma unroll
        for (int j = 0; j < 8; ++j)
            o[j] = f2h(src[(size_t)(kb + j) * 128 + n]);   // coalesced along n
        *(ushort8v*)&Wt[(size_t)mat * 16384 + n * 128 + kb] = o;
    }
}

// Decode scP -> sN, cN + scalar moments; cursor -> f32 deg.  grid 157
__global__ __launch_bounds__(256) void decode_kernel(
    const unsigned long long* __restrict__ scP, const unsigned* __restrict__ cursor,
    float* __restrict__ sN, float* __restrict__ cN, float* __restrict__ dgf,
    float* __restrict__ mom)
{
    int t = threadIdx.x;
    int i = blockIdx.x * 256 + t;
    float a0 = 0.f, a1 = 0.f, a2 = 0.f, a3 = 0.f, a4 = 0.f;
    if (i < N_NODES) {
        unsigned long long v = scP[i];
        unsigned cnt = (unsigned)(v & 0xFFFFFULL);
        long long sp = (long long)(v >> 20) - ((long long)cnt << 30);
        float s = (float)sp * (1.0f / 65536.0f);
        float c = (float)cnt;
        sN[i] = s; cN[i] = c;
        dgf[i] = (float)cursor[i];
        a0 = s; a1 = s * s; a2 = c; a3 = c * c; a4 = s * c;
    }
    #pragma unroll
    for (int off = 32; off > 0; off >>= 1) {
        a0 += __shfl_down(a0, off);
        a1 += __shfl_down(a1, off);
        a2 += __shfl_down(a2, off);
        a3 += __shfl_down(a3, off);
        a4 += __shfl_down(a4, off);
    }
    if ((t & 63) == 0) {
        atomicAdd(&mom[0], a0);
        atomicAdd(&mom[1], a1);
        atomicAdd(&mom[2], a2);
        atomicAdd(&mom[3], a3);
        atomicAdd(&mom[4], a4);
    }
}

// ---------------------------------------------------------------------------
// Gather with inline bn+relu: G[d] = sum relu(a*P[slot[d][j]]+b)
// Quarter-wave (16 lanes x 16B = one 256B row) per row; 2-deep unroll
// (R12-proven; 4-deep regressed via VGPR pressure — R14 lesson).
// ---------------------------------------------------------------------------
__global__ __launch_bounds__(256) void gather_bn_kernel(
    const unsigned* __restrict__ cnt, const unsigned short* __restrict__ slot,
    const unsigned short* __restrict__ Ph,
    const float* __restrict__ stat, const float* __restrict__ g_in,
    const float* __restrict__ bt_in,
    unsigned short* __restrict__ Gh)
{
    __shared__ float aT[128], bT[128];
    int t = threadIdx.x;
    bn_prep(stat, g_in, bt_in, aT, bT, t);
    __syncthreads();
    int wid = (blockIdx.x * 256 + t) >> 6;   // grid 10000 -> 40000 waves
    int lane = t & 63;
    int q = lane >> 4, l16 = lane & 15;
    int cb = l16 * 8;
    float av[8], bv[8];
    #pragma unroll
    for (int k = 0; k < 8; ++k) { av[k] = aT[cb + k]; bv[k] = bT[cb + k]; }
    int n = (int)cnt[wid];
    n = n < CAP ? n : CAP;
    const unsigned short* sl = &slot[(size_t)wid * CAP];
    float s0[8] = {0}, s1[8] = {0};
    int j = q;
    for (; j + 4 < n; j += 8) {
        int r0 = sl[j], r1 = sl[j + 4];
        ushort8v v0 = *(const ushort8v*)&Ph[(size_t)r0 * 128 + cb];
        ushort8v v1 = *(const ushort8v*)&Ph[(size_t)r1 * 128 + cb];
        #pragma unroll
        for (int k = 0; k < 8; ++k) {
            s0[k] += fmaxf(0.f, fmaf(h2f(v0[k]), av[k], bv[k]));
            s1[k] += fmaxf(0.f, fmaf(h2f(v1[k]), av[k], bv[k]));
        }
    }
    for (; j < n; j += 4) {
        int r0 = sl[j];
        ushort8v v0 = *(const ushort8v*)&Ph[(size_t)r0 * 128 + cb];
        #pragma unroll
        for (int k = 0; k < 8; ++k)
            s0[k] += fmaxf(0.f, fmaf(h2f(v0[k]), av[k], bv[k]));
    }
    #pragma unroll
    for (int k = 0; k < 8; ++k) {
        float v = s0[k] + s1[k];
        v += __shfl_xor(v, 16);
        v += __shfl_xor(v, 32);
        s0[k] = v;
    }
    if (q == 0) {
        ushort8v o;
        #pragma unroll
        for (int k = 0; k < 8; ++k) o[k] = f2h(s0[k]);
        *(ushort8v*)&Gh[(size_t)wid * 128 + cb] = o;
    }
}

// ---------------------------------------------------------------------------
// GEMM core: MFMA from afrag (regs) + swizzled LDS B, epilogue with bias,
// f16 write, sliced stats.  wave = 16 rows x 128 cols, 4 waves = 64 rows.
// ---------------------------------------------------------------------------
template<bool RSC>
__device__ __forceinline__ void gemm_core(
    int row0, int t, int slice, f16x8v afrag[4],
    const float* __restrict__ bias, const float* __restrict__ rowscale,
    unsigned short* __restrict__ Out, float* __restrict__ stats_out,
    const unsigned short* Bs, float (*redS)[128], float (*redQ)[128])
{
    const int w = t >> 6, lane = t & 63;
    const int la = lane & 15, lb = lane >> 4;
    const int kb = lb * 8;

    f32x4v acc[8];
    #pragma unroll
    for (int c = 0; c < 8; ++c) acc[c] = (f32x4v){0.f, 0.f, 0.f, 0.f};

    #pragma unroll
    for (int c = 0; c < 8; ++c) {
        int bn_ = (c << 4) + la;
        int bbase = bn_ * 128;
        int bswz = (bn_ & 7) << 3;
        #pragma unroll
        for (int s = 0; s < 4; ++s) {
            f16x8v bf = *(const f16x8v*)&Bs[(bbase + s * 32 + kb) ^ bswz];
            acc[c] = __builtin_amdgcn_mfma_f32_16x16x32_f16(
                afrag[s], bf, acc[c], 0, 0, 0);
        }
    }

    const int orow0 = row0 + (w << 4) + lb * 4;
    float rsj[4];
    if (RSC) {
        #pragma unroll
        for (int j = 0; j < 4; ++j) rsj[j] = rowscale[orow0 + j];
    }
    float csum[8], csq[8];
    #pragma unroll
    for (int c = 0; c < 8; ++c) {
        int col = (c << 4) + la;
        float bc = bias[col];
        float s0 = 0.f, s1 = 0.f;
        #pragma unroll
        for (int j = 0; j < 4; ++j) {
            float v = acc[c][j] + (RSC ? rsj[j] * bc : bc);
            Out[(size_t)(orow0 + j) * 128 + col] = f2h(v);
            s0 += v; s1 += v * v;
        }
        csum[c] = s0; csq[c] = s1;
    }
    #pragma unroll
    for (int c = 0; c < 8; ++c) {
        csum[c] += __shfl_xor(csum[c], 16);
        csum[c] += __shfl_xor(csum[c], 32);
        csq[c]  += __shfl_xor(csq[c], 16);
        csq[c]  += __shfl_xor(csq[c], 32);
    }
    if (lane < 16) {
        #pragma unroll
        for (int c = 0; c < 8; ++c) {
            redS[w][(c << 4) + lane] = csum[c];
            redQ[w][(c << 4) + lane] = csq[c];
        }
    }
    __syncthreads();
    float* stS = stats_out + slice * 256;
    if (t < 128) {
        atomicAdd(&stS[t], redS[0][t] + redS[1][t] + redS[2][t] + redS[3][t]);
        atomicAdd(&stS[128 + t], redQ[0][t] + redQ[1][t] + redQ[2][t] + redQ[3][t]);
    }
}

// Stage B (128x128 f16) into LDS with XOR swizzle (R5-proven pattern)
__device__ __forceinline__ void stage_B(
    const unsigned short* __restrict__ Wt, unsigned short* Bs, int t)
{
    #pragma unroll
    for (int i = 0; i < 8; ++i) {
        int cch = t + i * 256;
        int n = cch >> 4, off = (cch & 15) << 3;
        ushort8v w = *(const ushort8v*)&Wt[n * 128 + off];
        *(ushort8v*)&Bs[(n * 128 + off) ^ ((n & 7) << 3)] = w;
    }
}

// Load afrag from global A with optional transforms (AMODE 0/1/2)
template<int AMODE>
__device__ __forceinline__ void load_afrag_global(
    int row0, int t, f16x8v afrag[4],
    const unsigned short* __restrict__ A, const unsigned short* __restrict__ A2,
    const float* C1, const float* D1, const float* C2, const float* D2,
    const float* AE, const float* BE, const float* CE,
    const float* __restrict__ sN, const float* __restrict__ cN)
{
    const int w = t >> 6, lane = t & 63;
    const int la = lane & 15, lb = lane >> 4;
    const int ar = row0 + (w << 4) + la;
    const int kb = lb * 8;
    #pragma unroll
    for (int s = 0; s < 4; ++s) {
        ushort8v avv = *(const ushort8v*)&A[(size_t)ar * 128 + s * 32 + kb];
        if (AMODE == 0) {
            afrag[s] = __builtin_bit_cast(f16x8v, avv);
        } else if (AMODE == 1) {
            f16x8v o;
            #pragma unroll
            for (int j = 0; j < 8; ++j) {
                int qq = s * 32 + kb + j;
                o[j] = (_Float16)fmaxf(0.f, fmaf(h2f(avv[j]), C1[qq], D1[qq]));
            }
            afrag[s] = o;
        } else {
            ushort8v gv = *(const ushort8v*)&A2[(size_t)ar * 128 + s * 32 + kb];
            float sr = sN[ar], cr = cN[ar];
            f16x8v o;
            #pragma unroll
            for (int j = 0; j < 8; ++j) {
                int qq = s * 32 + kb + j;
                float y = h2f(avv[j]) * C1[qq] + D1[qq] + h2f(gv[j]) * C2[qq] + D2[qq]
                        + sr * AE[qq] + cr * BE[qq] + CE[qq];
                o[j] = (_Float16)fmaxf(0.f, y);
            }
            afrag[s] = o;
        }
    }
}

// ---------------------------------------------------------------------------
// Dual GEMM: blocks [0,GB) node branch (AMODE1), [GB,2GB) neighbor (AMODE0+RSC)
// ---------------------------------------------------------------------------
__global__ __launch_bounds__(256) void dual_gemm_kernel(
    const unsigned short* __restrict__ Ph, unsigned short* __restrict__ Gh,
    const unsigned short* __restrict__ WtZ, const unsigned short* __restrict__ WtG,
    const float* __restrict__ bZ, const float* __restrict__ bG,
    const float* __restrict__ dg,
    const float* __restrict__ st1, const float* __restrict__ g1,
    const float* __restrict__ bt1,
    unsigned short* __restrict__ ZNh,
    float* __restrict__ statZN, float* __restrict__ statG)
{
    __shared__ __align__(16) unsigned short Bs[128 * 128];
    __shared__ float C1[128], D1[128];
    __shared__ float redS[4][128], redQ[4][128];
    const int t = threadIdx.x;
    const int b = blockIdx.x;

    if (b < GB) {
        bn_prep(st1, g1, bt1, C1, D1, t);
        __syncthreads();
        const int row0 = b * 64;
        stage_B(WtZ, Bs, t);
        f16x8v afrag[4];
        load_afrag_global<1>(row0, t, afrag, Ph, nullptr,
                             C1, D1, nullptr, nullptr, nullptr, nullptr, nullptr,
                             nullptr, nullptr);
        __syncthreads();   // Bs staged; A reads done
        gemm_core<false>(row0, t, b & (NSLICE - 1), afrag, bZ, nullptr,
                         ZNh, statZN, Bs, redS, redQ);
    } else {
        const int row0 = (b - GB) * 64;
        stage_B(WtG, Bs, t);
        f16x8v afrag[4];
        load_afrag_global<0>(row0, t, afrag, Gh, nullptr,
                             nullptr, nullptr, nullptr, nullptr, nullptr,
                             nullptr, nullptr, nullptr, nullptr);
        __syncthreads();   // Bs staged; A reads done (in-place safe)
        gemm_core<true>(row0, t, b & (NSLICE - 1), afrag, bG, dg,
                        Gh, statG, Bs, redS, redQ);
    }
}

// ---------------------------------------------------------------------------
// Standalone GEMM (64-row tiles). grid GB x 256 thr.
// ---------------------------------------------------------------------------
template<int AMODE, bool RSC>
__global__ __launch_bounds__(256) void mfma_gemm_kernel(
    const unsigned short* __restrict__ A, const unsigned short* __restrict__ A2,
    const unsigned short* __restrict__ Wt,
    const float* __restrict__ bias, const float* __restrict__ rowscale,
    const float* __restrict__ st1, const float* __restrict__ g1, const float* __restrict__ bt1,
    const float* __restrict__ st2, const float* __restrict__ g2, const float* __restrict__ bt2,
    const float* __restrict__ sN, const float* __restrict__ cN,
    const float* __restrict__ scal,
    const float* __restrict__ We, const float* __restrict__ Be,
    const float* __restrict__ ge, const float* __restrict__ bte,
    unsigned short* __restrict__ Out, float* __restrict__ stats_out)
{
    __shared__ __align__(16) unsigned short Bs[128 * 128];
    __shared__ float C1[128], D1[128], C2[128], D2[128];
    __shared__ float AE[128], BE[128], CE[128];
    __shared__ float redS[4][128], redQ[4][128];
    const int t = threadIdx.x;

    if (AMODE >= 1) {
        bn_prep(st1, g1, bt1, C1, D1, t);
    }
    if (AMODE == 2) {
        bn_prep(st2, g2, bt2, C2, D2, t);
        if (t < 128) {
            float ms = scal[0] * RCP_N, vs = scal[1] * RCP_N - ms * ms;
            float mc = scal[2] * RCP_N, vc = scal[3] * RCP_N - mc * mc;
            float cov = scal[4] * RCP_N - ms * mc;
            float we = We[t], be = Be[t];
            float me = ms * we + mc * be;
            float ve = we * we * vs + be * be * vc + 2.f * we * be * cov;
            float ae = ge[t] * rsqrtf(ve + BN_EPS);
            AE[t] = we * ae; BE[t] = be * ae; CE[t] = bte[t] - me * ae;
        }
    }
    if (AMODE >= 1) __syncthreads();

    const int row0 = blockIdx.x * 64;
    stage_B(Wt, Bs, t);
    f16x8v afrag[4];
    load_afrag_global<AMODE>(row0, t, afrag, A, A2,
                             C1, D1, C2, D2, AE, BE, CE, sN, cN);
    // one barrier: Bs staged AND all A/A2 reads of this 64-row tile complete
    // (vmcnt drained before s_barrier) before in-place epilogue writes
    __syncthreads();
    gemm_core<RSC>(row0, t, blockIdx.x & (NSLICE - 1), afrag, bias, rowscale,
                   Out, stats_out, Bs, redS, redQ);
}

// Final elementwise: out(f32) = relu(bn(Z f16)), sliced stats input
__global__ __launch_bounds__(256) void bnrelu_kernel(
    const unsigned short* __restrict__ Z, const float* __restrict__ stz,
    const float* __restrict__ g, const float* __restrict__ bt,
    float* __restrict__ O)
{
    __shared__ float aT[128], bT[128];
    int t = threadIdx.x;
    bn_prep(stz, g, bt, aT, bT, t);
    __syncthreads();
    int stride = gridDim.x * 256;
    for (int idx = blockIdx.x * 256 + t; idx < N_NODES * 32; idx += stride) {
        int r = idx >> 5;
        int q = (idx & 31) * 4;
        ushort4 z = *(const ushort4*)&Z[(size_t)r * 128 + q];
        float4 o;
        o.x = fmaxf(0.f, fmaf(h2f(z.x), aT[q],     bT[q]));
        o.y = fmaxf(0.f, fmaf(h2f(z.y), aT[q + 1], bT[q + 1]));
        o.z = fmaxf(0.f, fmaf(h2f(z.z), aT[q + 2], bT[q + 2]));
        o.w = fmaxf(0.f, fmaf(h2f(z.w), aT[q + 3], bT[q + 3]));
        *(float4*)&O[(size_t)r * 128 + q] = o;
    }
}

// ---------------------------------------------------------------------------
extern "C" void kernel_launch(void* const* d_in, const int* in_sizes, int n_in,
                              void* d_out, int out_size, void* d_ws, size_t ws_size,
                              hipStream_t stream)
{
    const float* node_attr = (const float*)d_in[0];
    const int*   ei        = (const int*)d_in[1];
    const float* ea        = (const float*)d_in[2];
    const float* W0    = (const float*)d_in[3];
    const float* b0    = (const float*)d_in[4];
    const float* g0    = (const float*)d_in[5];
    const float* bt0   = (const float*)d_in[6];
    const float* Wnode = (const float*)d_in[7];
    const float* bnode = (const float*)d_in[8];
    const float* Wedge = (const float*)d_in[9];
    const float* bedge = (const float*)d_in[10];
    const float* Wnb   = (const float*)d_in[11];
    const float* bnb   = (const float*)d_in[12];
    const float* gn    = (const float*)d_in[13];
    const float* ge    = (const float*)d_in[14];
    const float* gnb   = (const float*)d_in[15];
    const float* gm1   = (const float*)d_in[16];
    const float* gm2   = (const float*)d_in[17];
    const float* btn   = (const float*)d_in[18];
    const float* bte   = (const float*)d_in[19];
    const float* btnb  = (const float*)d_in[20];
    const float* btm1  = (const float*)d_in[21];
    const float* btm2  = (const float*)d_in[22];
    const float* Wm1   = (const float*)d_in[23];
    const float* bm1   = (const float*)d_in[24];
    const float* Wm2   = (const float*)d_in[25];
    const float* bm2   = (const float*)d_in[26];
    float* out = (float*)d_out;

    // workspace: Ph|ZNh|Gh (f16, NF each) | sN|cN|dg (f32) | st(sliced stats)
    //            | scP(u64,N) | cursor(u32,N) | slot(u16, N*CAP) | Wtb(f16)
    unsigned short* Ph  = (unsigned short*)d_ws;
    unsigned short* ZNh = Ph + NF;
    unsigned short* Gh  = ZNh + NF;
    float* sN = (float*)(Gh + NF);
    float* cN = sN + N_NODES;
    float* dg = cN + N_NODES;
    float* st = dg + N_NODES;
    // st layout: [0..4] moments | [256..256+STB) init stats |
    //            layer i stat j at 256+STB + (i*4+j)*STB  (j: zn,aggr,z1,z2)
    const size_t ST_FLOATS = 256 + (size_t)STB * 13;
    unsigned long long* scP = (unsigned long long*)(st + ST_FLOATS);
    unsigned* cursor = (unsigned*)(scP + N_NODES);
    unsigned short* slot = (unsigned short*)(cursor + N_NODES);
    unsigned short* Wtb = slot + (size_t)N_NODES * CAP;
    float* stInit = st + 256;
    float* layBase = st + 256 + STB;

    // zero st | scP | cursor (contiguous)
    (void)hipMemsetAsync(st, 0, (ST_FLOATS + 3 * (size_t)N_NODES) * sizeof(float), stream);
    edge_init_kernel<<<3221, 256, 0, stream>>>(
        node_attr, W0, b0, Ph, stInit, ei, ea, scP, cursor, slot,
        Wnode, Wnb, Wm1, Wm2, Wtb);
    decode_kernel<<<157, 256, 0, stream>>>(scP, cursor, sN, cN, dg, st);

    const float* xst = stInit;
    const float* xg  = g0;
    const float* xbt = bt0;

    for (int i = 0; i < 3; ++i) {
        float* lay = layBase + (size_t)i * 4 * STB;
        // G = sum over in-neighbors of relu(bn(P[src]))
        gather_bn_kernel<<<10000, 256, 0, stream>>>(cursor, slot, Ph, xst, xg, xbt, Gh);
        // dual: ZN = relu(bn(P)) @ Wnode + bnode  ||  G = G @ Wnb + deg*bnb
        dual_gemm_kernel<<<2 * GB, 256, 0, stream>>>(
            Ph, Gh,
            Wtb + (size_t)(0 + i) * 16384, Wtb + (size_t)(3 + i) * 16384,
            bnode + i * 128, bnb + i * 128, dg,
            xst, xg, xbt,
            ZNh, lay, lay + STB);
        // z1 = relu(bn(ZN)+bn(G)+ea) @ Wm1 + bm1 (+stats) -> ZN (fused combine)
        mfma_gemm_kernel<2, false><<<GB, 256, 0, stream>>>(
            ZNh, Gh, Wtb + (size_t)(6 + i) * 16384, bm1 + i * 128, nullptr,
            lay, gn + i * 128, btn + i * 128,
            lay + STB, gnb + i * 128, btnb + i * 128,
            sN, cN, st,
            Wedge + i * 128, bedge + i * 128, ge + i * 128, bte + i * 128,
            ZNh, lay + 2 * STB);
        // z2 = relu(bn(z1)) @ Wm2 + bm2 (+stats) -> P
        mfma_gemm_kernel<1, false><<<GB, 256, 0, stream>>>(
            ZNh, nullptr, Wtb + (size_t)(9 + i) * 16384, bm2 + i * 128, nullptr,
            lay + 2 * STB, gm1 + i * 128, btm1 + i * 128, nullptr, nullptr, nullptr,
            nullptr, nullptr, nullptr, nullptr, nullptr, nullptr, nullptr,
            Ph, lay + 3 * STB);

        xst = lay + 3 * STB;
        xg  = gm2 + i * 128;
        xbt = btm2 + i * 128;
    }
    bnrelu_kernel<<<2048, 256, 0, stream>>>(Ph, xst, xg, xbt, out);
}